// Round 3
// baseline (4619.477 us; speedup 1.0000x reference)
//
#include <hip/hip_runtime.h>
#include <hip/hip_bf16.h>
#include <math.h>

// Problem constants (B=4, 128x128 grid, DIM=256, 8 heads x 64)
#define NB 4
#define NY 128
#define NX 128
#define DIM 256
#define NH 8
#define DH_ 64
#define HDIM 512   // NH*DH
#define HID 1024
#define NPOS (NB*NY*NX)   // 65536

typedef __hip_bfloat16 bf16_t;
__device__ __forceinline__ float b2f(bf16_t x){ return __bfloat162float(x); }
__device__ __forceinline__ bf16_t f2b(float x){ return __float2bfloat16(x); }

// Round-2 evidence: inputs/outputs are FLOAT32 (ln1_g[0] == 0x3F800000).
// Internal staging of the two big tensors (un, phi) stays bf16 (2% absmax budget).

__device__ __forceinline__ float gelu_tanh(float x){
  float x3 = x*x*x;
  return 0.5f*x*(1.0f + tanhf(0.7978845608028654f*(x + 0.044715f*x3)));
}

// ---------------------------------------------------------------- LN1 (f32 in -> bf16 un)
__global__ void __launch_bounds__(256) k_ln1(const float* __restrict__ u,
    const float* __restrict__ g, const float* __restrict__ b,
    bf16_t* __restrict__ un){
  int wave = threadIdx.x >> 6, lane = threadIdx.x & 63;
  size_t row = (size_t)blockIdx.x*4 + wave;
  const float* x = u + row*DIM;
  float v[4]; float s=0.f, ss=0.f;
  #pragma unroll
  for (int j=0;j<4;j++){ float t = x[lane + j*64]; v[j]=t; s+=t; ss+=t*t; }
  #pragma unroll
  for (int off=32;off>0;off>>=1){ s += __shfl_down(s,off,64); ss += __shfl_down(ss,off,64); }
  s = __shfl(s,0,64); ss = __shfl(ss,0,64);
  float m = s*(1.0f/DIM);
  float var = ss*(1.0f/DIM) - m*m;
  float r = rsqrtf(var + 1e-5f);
  bf16_t* o = un + row*DIM;
  #pragma unroll
  for (int j=0;j<4;j++){
    int f = lane + j*64;
    o[f] = f2b((v[j]-m)*r*g[f] + b[f]);
  }
}

// ---------------------------------------------------------------- pooling (bf16 un -> f32)
__global__ void __launch_bounds__(256) k_pool_y(const bf16_t* __restrict__ un, float* __restrict__ pooly){
  int by = blockIdx.x;          // b*NY + y
  int d = threadIdx.x;
  size_t base = (size_t)by*NX*DIM + d;
  float s = 0.f;
  for (int x=0;x<NX;x++) s += b2f(un[base + (size_t)x*DIM]);
  pooly[(size_t)by*DIM + d] = s*(1.0f/NX);
}
__global__ void __launch_bounds__(256) k_pool_x(const bf16_t* __restrict__ un, float* __restrict__ poolx){
  int bb = blockIdx.x / NX, x = blockIdx.x % NX;
  int d = threadIdx.x;
  size_t base = ((size_t)bb*NY*NX + x)*DIM + d;
  float s = 0.f;
  for (int y=0;y<NY;y++) s += b2f(un[base + (size_t)y*NX*DIM]);
  poolx[(size_t)blockIdx.x*DIM + d] = s*(1.0f/NY);
}

// ---------------------------------------------------------------- small GEMM (all f32)
__global__ void __launch_bounds__(256) k_gemm_small(const float* __restrict__ A,
    const float* __restrict__ W, const float* __restrict__ bias,
    float* __restrict__ C, int M, int N, int K, int dogelu){
  int idx = blockIdx.x*256 + threadIdx.x;
  if (idx >= M*N) return;
  int n = idx % N, m = idx / N;
  const float* a = A + (size_t)m*K;
  float acc = 0.f;
  for (int k=0;k<K;k++) acc += a[k]*W[(size_t)k*N + n];
  if (bias) acc += bias[n];
  if (dogelu) acc = gelu_tanh(acc);
  C[idx] = acc;
}

// ---------------------------------------------------------------- RoPE split
__global__ void __launch_bounds__(256) k_rope(const float* __restrict__ qk,
    const float* __restrict__ cs, const float* __restrict__ sn,
    float* __restrict__ q, float* __restrict__ k){
  int idx = blockIdx.x*256 + threadIdx.x;   // < NB*128*1024
  int c = idx & 63;
  int h = (idx>>6) & 7;
  int p = (idx>>9) & 1;
  int n = (idx>>10) & 127;
  int bb = idx>>17;
  float t = qk[idx];
  float t2 = qk[(c<32) ? idx+32 : idx-32];
  if (c<32) t2 = -t2;
  float val = t*cs[n*64+c] + t2*sn[n*64+c];
  float* dst = p ? k : q;
  dst[(((size_t)bb*NH + h)*128 + n)*64 + c] = val;
}

// ---------------------------------------------------------------- attention matrix
__global__ void __launch_bounds__(128) k_attn(const float* __restrict__ q,
    const float* __restrict__ k, float* __restrict__ attn){
  int i = blockIdx.x & 127;
  int bh = blockIdx.x >> 7;
  __shared__ float qs[64];
  __shared__ float sm[128];
  int tid = threadIdx.x;
  const float* qrow = q + ((size_t)bh*128 + i)*64;
  if (tid < 64) qs[tid] = qrow[tid];
  __syncthreads();
  const float* krow = k + ((size_t)bh*128 + tid)*64;
  float dot = 0.f;
  for (int c=0;c<64;c++) dot += qs[c]*krow[c];
  dot *= (1.0f/64.0f);
  sm[tid] = dot;
  __syncthreads();
  float mx = -1e30f;
  for (int j=0;j<128;j++) mx = fmaxf(mx, sm[j]);
  __syncthreads();
  float e = expf(dot - mx);
  sm[tid] = e;
  __syncthreads();
  float s = 0.f;
  for (int j=0;j<128;j++) s += sm[j];
  attn[(size_t)blockIdx.x*128 + tid] = e/s;
}

// ---------------------------------------------------------------- fused V-projection + y-attention
// block (bh, m=x): v[y][c] = un[b,y,m,:] @ Wv[:, h*64+c]
//                  phi[bh, i, m, c] = sum_j attnY[bh,i,j] * v[j][c]
__global__ void __launch_bounds__(256) k_phi1v(const bf16_t* __restrict__ un,
    const float* __restrict__ Wv, const float* __restrict__ attn,
    bf16_t* __restrict__ phi){
  int m  = blockIdx.x & (NX-1);
  int bh = blockIdx.x >> 7;
  int b  = bh >> 3, h = bh & 7;
  __shared__ __align__(16) bf16_t un_s[128*64];  // [y][k-chunk]  16KB
  __shared__ __align__(16) float  wv_s[64*64];   // [k][c]        16KB
  __shared__ __align__(16) float  v_s[128*64];   //               32KB
  int tid = threadIdx.x;
  int c  = tid & 63;
  int yb = tid >> 6;            // 0..3

  float vacc[32];
  #pragma unroll
  for (int i=0;i<32;i++) vacc[i]=0.f;

  for (int kc=0; kc<4; kc++){
    // stage un chunk: rows y=0..127, cols k=kc*64..+63 (2048 x ushort4)
    {
      const ushort* ug = (const ushort*)un;
      ushort4* dst = (ushort4*)un_s;
      #pragma unroll
      for (int j=0;j<8;j++){
        int q = tid + j*256;
        int y = q >> 4, c4 = q & 15;
        size_t ga = (((size_t)b*NY + y)*NX + m)*DIM + kc*64 + c4*4;
        dst[q] = *(const ushort4*)(ug + ga);
      }
      // stage Wv chunk: rows k=0..63, cols h*64..h*64+63 (1024 x float4)
      float4* wdst = (float4*)wv_s;
      #pragma unroll
      for (int j=0;j<4;j++){
        int q = tid + j*256;
        int k = q >> 4, c4 = q & 15;
        size_t ga = ((size_t)(kc*64 + k))*HDIM + h*64 + c4*4;
        wdst[q] = *(const float4*)(Wv + ga);
      }
    }
    __syncthreads();
    float w[64];
    #pragma unroll
    for (int k=0;k<64;k++) w[k] = wv_s[k*64 + c];
    #pragma unroll
    for (int i=0;i<32;i++){
      const ushort4* row = (const ushort4*)&un_s[(yb*32+i)*64];
      float a = vacc[i];
      #pragma unroll
      for (int j=0;j<16;j++){
        ushort4 u4 = row[j];
        a += b2f(*(const bf16_t*)&u4.x)*w[j*4+0] + b2f(*(const bf16_t*)&u4.y)*w[j*4+1]
           + b2f(*(const bf16_t*)&u4.z)*w[j*4+2] + b2f(*(const bf16_t*)&u4.w)*w[j*4+3];
      }
      vacc[i] = a;
    }
    __syncthreads();
  }
  #pragma unroll
  for (int i=0;i<32;i++) v_s[(yb*32+i)*64 + c] = vacc[i];
  __syncthreads();

  // y-attention: phi[bh, i0+i, m, c] = sum_j attn[bh, i0+i, j] * v_s[j][c]
  int i0 = yb*32;
  const float* arow = attn + (size_t)bh*16384 + (size_t)i0*128;
  float acc[32];
  #pragma unroll
  for (int i=0;i<32;i++) acc[i]=0.f;
  for (int j=0;j<128;j++){
    float vv = v_s[j*64 + c];
    #pragma unroll
    for (int i=0;i<32;i++) acc[i] += arow[i*128 + j]*vv;
  }
  bf16_t* pout = phi + ((size_t)bh*NY + i0)*(NX*DH_) + (size_t)m*DH_ + c;
  #pragma unroll
  for (int i=0;i<32;i++) pout[(size_t)i*(NX*DH_)] = f2b(acc[i]);
}

// ---------------------------------------------------------------- phi2 (x-attention, in place)
__global__ void __launch_bounds__(256) k_phi2(const float* __restrict__ attn,
    bf16_t* __restrict__ phi){
  int i = blockIdx.x & (NY-1);
  int bh = blockIdx.x >> 7;
  __shared__ float ps[128*64];
  int tid = threadIdx.x;
  bf16_t* pblk = phi + ((size_t)bh*NY + i)*(NX*DH_);
  for (int t=tid; t<8192; t+=256) ps[t] = b2f(pblk[t]);
  __syncthreads();
  int c = tid & 63;
  int l0 = (tid >> 6) * 32;
  const float* arow = attn + (size_t)bh*16384 + (size_t)l0*128;
  float acc[32];
  #pragma unroll
  for (int l=0;l<32;l++) acc[l]=0.f;
  for (int mm=0; mm<128; mm++){
    float vv = ps[mm*64 + c];
    #pragma unroll
    for (int l=0;l<32;l++) acc[l] += arow[l*128 + mm]*vv;
  }
  #pragma unroll
  for (int l=0;l<32;l++) pblk[(size_t)(l0+l)*DH_ + c] = f2b(acc[l]);
}

// ---------------------------------------------------------------- GroupNorm + Wm + residual -> u2 (f32, in d_out)
__global__ void __launch_bounds__(256) k_gn_wm(const bf16_t* __restrict__ phi,
    const float* __restrict__ Wm, const float* __restrict__ bm,
    const float* __restrict__ u, float* __restrict__ u2){
  size_t p0 = (size_t)blockIdx.x*8;
  __shared__ __align__(16) float xg[8*512];
  __shared__ float mean_[64], rstd_[64];
  int tid = threadIdx.x;
  for (int t=tid; t<4096; t+=256){
    int r = t>>9, f = t&511;
    size_t p = p0 + r;
    int l = (int)(p & 127); size_t bi = p>>7; int i = (int)(bi & 127); int bb = (int)(bi>>7);
    int h = f>>6, c = f&63;
    xg[t] = b2f(phi[((((size_t)bb*NH+h)*NY+i)*NX+l)*DH_ + c]);
  }
  __syncthreads();
  if (tid < 64){
    int base = tid*64;
    float s=0.f, ss=0.f;
    for (int cc=0; cc<64; cc++){
      int c = (cc + tid) & 63;
      float t = xg[base + c];
      s += t; ss += t*t;
    }
    float mm = s*(1.0f/64.0f);
    float vv = ss*(1.0f/64.0f) - mm*mm;
    mean_[tid] = mm;
    rstd_[tid] = rsqrtf(vv + 1e-6f);
  }
  __syncthreads();
  for (int t=tid; t<4096; t+=256){
    int g = t>>6;
    xg[t] = (xg[t]-mean_[g])*rstd_[g];
  }
  __syncthreads();
  int rh = tid>>7;
  int n0 = tid & 127;
  float acc[4][2];
  #pragma unroll
  for (int r=0;r<4;r++){ acc[r][0]=0.f; acc[r][1]=0.f; }
  for (int k4=0;k4<128;k4++){
    float w0[4], w1[4];
    #pragma unroll
    for (int kk=0;kk<4;kk++){
      w0[kk] = Wm[(size_t)(k4*4+kk)*DIM + n0];
      w1[kk] = Wm[(size_t)(k4*4+kk)*DIM + n0 + 128];
    }
    #pragma unroll
    for (int r=0;r<4;r++){
      float4 x = *(const float4*)&xg[(rh*4+r)*512 + k4*4];
      acc[r][0] += x.x*w0[0] + x.y*w0[1] + x.z*w0[2] + x.w*w0[3];
      acc[r][1] += x.x*w1[0] + x.y*w1[1] + x.z*w1[2] + x.w*w1[3];
    }
  }
  float bm0 = bm[n0], bm1 = bm[n0+128];
  #pragma unroll
  for (int r=0;r<4;r++){
    size_t p = p0 + rh*4 + r;
    u2[p*DIM + n0]       = acc[r][0] + bm0 + u[p*DIM + n0];
    u2[p*DIM + n0 + 128] = acc[r][1] + bm1 + u[p*DIM + n0 + 128];
  }
}

// ---------------------------------------------------------------- LN2 + MLP + residual (u2 in d_out, in place)
__global__ void __launch_bounds__(256) k_mlp_out(const float* u2,
    const float* __restrict__ g2, const float* __restrict__ b2,
    const float* __restrict__ Wf1, const float* __restrict__ bf1,
    const float* __restrict__ Wf2, const float* __restrict__ bf2,
    float* out){
  size_t p0 = (size_t)blockIdx.x*8;
  __shared__ __align__(16) float xr[8*256];
  __shared__ __align__(16) float xln[8*256];
  __shared__ __align__(16) float hb[8*1024];
  __shared__ float ms[8], rs[8];
  int tid = threadIdx.x;
  for (int t=tid; t<2048; t+=256) xr[t] = u2[p0*DIM + t];
  __syncthreads();
  if (tid < 8){
    int base = tid*256;
    float s=0.f, ss=0.f;
    for (int cc=0; cc<256; cc++){
      int c = (cc + tid*32) & 255;
      float t = xr[base + c]; s += t; ss += t*t;
    }
    float mm = s*(1.0f/256.0f);
    float vv = ss*(1.0f/256.0f) - mm*mm;
    ms[tid] = mm; rs[tid] = rsqrtf(vv + 1e-5f);
  }
  __syncthreads();
  for (int t=tid; t<2048; t+=256){
    int r = t>>8, c = t&255;
    xln[t] = (xr[t]-ms[r])*rs[r]*g2[c] + b2[c];
  }
  __syncthreads();
  float hacc[4][8];
  #pragma unroll
  for (int jj=0;jj<4;jj++)
    #pragma unroll
    for (int r=0;r<8;r++) hacc[jj][r]=0.f;
  for (int k4=0;k4<64;k4++){
    float xv[8][4];
    #pragma unroll
    for (int r=0;r<8;r++){
      float4 t = *(const float4*)&xln[r*256 + k4*4];
      xv[r][0]=t.x; xv[r][1]=t.y; xv[r][2]=t.z; xv[r][3]=t.w;
    }
    #pragma unroll
    for (int kk=0;kk<4;kk++){
      #pragma unroll
      for (int jj=0;jj<4;jj++){
        float wv = Wf1[(size_t)(k4*4+kk)*HID + (jj<<8) + tid];
        #pragma unroll
        for (int r=0;r<8;r++) hacc[jj][r] += xv[r][kk]*wv;
      }
    }
  }
  #pragma unroll
  for (int jj=0;jj<4;jj++){
    int n = (jj<<8) + tid;
    float bb = bf1[n];
    #pragma unroll
    for (int r=0;r<8;r++) hb[(r<<10)+n] = gelu_tanh(hacc[jj][r] + bb);
  }
  __syncthreads();
  int rh = tid>>7, n0 = tid&127;
  float acc[4][2];
  #pragma unroll
  for (int r=0;r<4;r++){ acc[r][0]=0.f; acc[r][1]=0.f; }
  for (int k4=0;k4<256;k4++){
    float hv[4][4];
    #pragma unroll
    for (int r=0;r<4;r++){
      float4 t = *(const float4*)&hb[((rh*4+r)<<10) + k4*4];
      hv[r][0]=t.x; hv[r][1]=t.y; hv[r][2]=t.z; hv[r][3]=t.w;
    }
    #pragma unroll
    for (int kk=0;kk<4;kk++){
      float w0 = Wf2[(size_t)(k4*4+kk)*DIM + n0];
      float w1 = Wf2[(size_t)(k4*4+kk)*DIM + n0 + 128];
      #pragma unroll
      for (int r=0;r<4;r++){
        acc[r][0] += hv[r][kk]*w0;
        acc[r][1] += hv[r][kk]*w1;
      }
    }
  }
  float bb0 = bf2[n0], bb1 = bf2[n0+128];
  #pragma unroll
  for (int r=0;r<4;r++){
    int row = rh*4 + r;
    size_t p = p0 + row;
    out[p*DIM + n0]       = acc[r][0] + bb0 + xr[(row<<8) + n0];
    out[p*DIM + n0 + 128] = acc[r][1] + bb1 + xr[(row<<8) + n0 + 128];
  }
}

extern "C" void kernel_launch(void* const* d_in, const int* in_sizes, int n_in,
                              void* d_out, int out_size, void* d_ws, size_t ws_size,
                              hipStream_t stream){
  const float* u    = (const float*)d_in[0];
  const float* rcy  = (const float*)d_in[1];
  const float* rsy  = (const float*)d_in[2];
  const float* rcx  = (const float*)d_in[3];
  const float* rsx  = (const float*)d_in[4];
  const float* ln1g = (const float*)d_in[6];
  const float* ln1b = (const float*)d_in[7];
  const float* ln2g = (const float*)d_in[8];
  const float* ln2b = (const float*)d_in[9];
  const float* Wv   = (const float*)d_in[10];
  const float* Wyin = (const float*)d_in[11];
  const float* Wy1  = (const float*)d_in[12];
  const float* by1  = (const float*)d_in[13];
  const float* Wy2  = (const float*)d_in[14];
  const float* by2  = (const float*)d_in[15];
  const float* Wxin = (const float*)d_in[16];
  const float* Wx1  = (const float*)d_in[17];
  const float* bx1  = (const float*)d_in[18];
  const float* Wx2  = (const float*)d_in[19];
  const float* bx2  = (const float*)d_in[20];
  const float* Wqkx = (const float*)d_in[21];
  const float* Wqky = (const float*)d_in[22];
  const float* Wm   = (const float*)d_in[23];
  const float* bm   = (const float*)d_in[24];
  const float* Wf1  = (const float*)d_in[25];
  const float* bf1  = (const float*)d_in[26];
  const float* Wf2  = (const float*)d_in[27];
  const float* bf2  = (const float*)d_in[28];

  char* w = (char*)d_ws;
  auto alloc = [&](size_t n) -> void* {
    void* p = (void*)w;
    w += (n + 255) & ~(size_t)255;
    return p;
  };
  // total ~115 MB
  bf16_t* UN   = (bf16_t*)alloc((size_t)NPOS*DIM*2);               // 32 MiB
  bf16_t* PHI  = (bf16_t*)alloc((size_t)NB*NH*NY*NX*DH_*2);        // 64 MiB
  float* POOLY = (float*)alloc((size_t)NB*NY*DIM*4);
  float* POOLX = (float*)alloc((size_t)NB*NX*DIM*4);
  float* TY    = (float*)alloc((size_t)512*256*4);
  float* TX    = (float*)alloc((size_t)512*256*4);
  float* HY    = (float*)alloc((size_t)512*1024*4);
  float* HX    = (float*)alloc((size_t)512*1024*4);
  float* UY    = (float*)alloc((size_t)512*256*4);
  float* UX    = (float*)alloc((size_t)512*256*4);
  float* QKY   = (float*)alloc((size_t)512*1024*4);
  float* QKX   = (float*)alloc((size_t)512*1024*4);
  float* QRY   = (float*)alloc((size_t)NB*NH*128*64*4);
  float* KRY   = (float*)alloc((size_t)NB*NH*128*64*4);
  float* QRX   = (float*)alloc((size_t)NB*NH*128*64*4);
  float* KRX   = (float*)alloc((size_t)NB*NH*128*64*4);
  float* ATTNY = (float*)alloc((size_t)NB*NH*128*128*4);
  float* ATTNX = (float*)alloc((size_t)NB*NH*128*128*4);
  float* U2 = (float*)d_out;   // u2 lives in d_out (f32, in-place for final MLP)
  (void)in_sizes; (void)n_in; (void)out_size; (void)ws_size;

  k_ln1<<<NPOS/4, 256, 0, stream>>>(u, ln1g, ln1b, UN);
  k_pool_y<<<NB*NY, 256, 0, stream>>>(UN, POOLY);
  k_pool_x<<<NB*NX, 256, 0, stream>>>(UN, POOLX);
  k_gemm_small<<<(512*256)/256, 256, 0, stream>>>(POOLY, Wyin, (const float*)nullptr, TY, 512, 256, 256, 0);
  k_gemm_small<<<(512*1024)/256, 256, 0, stream>>>(TY, Wy1, by1, HY, 512, 1024, 256, 1);
  k_gemm_small<<<(512*256)/256, 256, 0, stream>>>(HY, Wy2, by2, UY, 512, 256, 1024, 0);
  k_gemm_small<<<(512*1024)/256, 256, 0, stream>>>(UY, Wqky, (const float*)nullptr, QKY, 512, 1024, 256, 0);
  k_gemm_small<<<(512*256)/256, 256, 0, stream>>>(POOLX, Wxin, (const float*)nullptr, TX, 512, 256, 256, 0);
  k_gemm_small<<<(512*1024)/256, 256, 0, stream>>>(TX, Wx1, bx1, HX, 512, 1024, 256, 1);
  k_gemm_small<<<(512*256)/256, 256, 0, stream>>>(HX, Wx2, bx2, UX, 512, 256, 1024, 0);
  k_gemm_small<<<(512*1024)/256, 256, 0, stream>>>(UX, Wqkx, (const float*)nullptr, QKX, 512, 1024, 256, 0);
  k_rope<<<(NB*128*1024)/256, 256, 0, stream>>>(QKY, rcy, rsy, QRY, KRY);
  k_rope<<<(NB*128*1024)/256, 256, 0, stream>>>(QKX, rcx, rsx, QRX, KRX);
  k_attn<<<NB*NH*128, 128, 0, stream>>>(QRY, KRY, ATTNY);
  k_attn<<<NB*NH*128, 128, 0, stream>>>(QRX, KRX, ATTNX);
  k_phi1v<<<NB*NH*NX, 256, 0, stream>>>(UN, Wv, ATTNY, PHI);
  k_phi2<<<NB*NH*NY, 256, 0, stream>>>(ATTNX, PHI);
  k_gn_wm<<<NPOS/8, 256, 0, stream>>>(PHI, Wm, bm, u, U2);
  k_mlp_out<<<NPOS/8, 256, 0, stream>>>(U2, ln2g, ln2b, Wf1, bf1, Wf2, bf2, (float*)d_out);
}

// Round 4
// 3226.080 us; speedup vs baseline: 1.4319x; 1.4319x over previous
//
#include <hip/hip_runtime.h>
#include <hip/hip_bf16.h>
#include <math.h>

// Problem constants (B=4, 128x128 grid, DIM=256, 8 heads x 64)
#define NB 4
#define NY 128
#define NX 128
#define DIM 256
#define NH 8
#define DH_ 64
#define HDIM 512   // NH*DH
#define HID 1024
#define NPOS (NB*NY*NX)   // 65536

typedef __hip_bfloat16 bf16_t;
typedef __attribute__((ext_vector_type(8))) short short8;   // 8 bf16 = 1 MFMA A/B frag
typedef __attribute__((ext_vector_type(4))) float f32x4;    // MFMA C/D frag

__device__ __forceinline__ float b2f(bf16_t x){ return __bfloat162float(x); }
__device__ __forceinline__ bf16_t f2b(float x){ return __float2bfloat16(x); }
__device__ __forceinline__ short f2s(float x){ bf16_t h = __float2bfloat16(x); return *reinterpret_cast<short*>(&h); }
__device__ __forceinline__ float s2f(short x){ bf16_t h = *reinterpret_cast<bf16_t*>(&x); return __bfloat162float(h); }

// MFMA fragment layout (gfx950, verified per guide m89/m120):
//  A[m][k]: m = lane&15, k = (lane>>4)*8 + j
//  B[k][n]: n = lane&15, k = (lane>>4)*8 + j
//  D[row][col]: col = lane&15, row = (lane>>4)*4 + reg

__device__ __forceinline__ float gelu_tanh(float x){
  float x3 = x*x*x;
  return 0.5f*x*(1.0f + tanhf(0.7978845608028654f*(x + 0.044715f*x3)));
}

// ---------------------------------------------------------------- weight pack
// W[K x N] f32 row-major -> bf16 B-fragment order:
// out[((kb*(N/16) + nt)*64 + lane)*8 + j] = W[(kb*32 + (lane>>4)*8 + j)*N + nt*16 + (lane&15)]
__global__ void __launch_bounds__(256) k_pack(const float* __restrict__ W,
    short* __restrict__ out, int K, int N){
  int tid = blockIdx.x*256 + threadIdx.x;      // < K*N/8
  int lane = tid & 63;
  int rem = tid >> 6;
  int ntiles = N >> 4;
  int nt = rem % ntiles, kb = rem / ntiles;
  int n = nt*16 + (lane & 15);
  int k0 = kb*32 + (lane>>4)*8;
  short8 v;
  #pragma unroll
  for (int j=0;j<8;j++) v[j] = f2s(W[(size_t)(k0+j)*N + n]);
  *(short8*)&out[(size_t)tid*8] = v;
}

// ---------------------------------------------------------------- LN1 (f32 in -> bf16 un)
__global__ void __launch_bounds__(256) k_ln1(const float* __restrict__ u,
    const float* __restrict__ g, const float* __restrict__ b,
    bf16_t* __restrict__ un){
  int wave = threadIdx.x >> 6, lane = threadIdx.x & 63;
  size_t row = (size_t)blockIdx.x*4 + wave;
  const float* x = u + row*DIM;
  float v[4]; float s=0.f, ss=0.f;
  #pragma unroll
  for (int j=0;j<4;j++){ float t = x[lane + j*64]; v[j]=t; s+=t; ss+=t*t; }
  #pragma unroll
  for (int off=32;off>0;off>>=1){ s += __shfl_down(s,off,64); ss += __shfl_down(ss,off,64); }
  s = __shfl(s,0,64); ss = __shfl(ss,0,64);
  float m = s*(1.0f/DIM);
  float var = ss*(1.0f/DIM) - m*m;
  float r = rsqrtf(var + 1e-5f);
  bf16_t* o = un + row*DIM;
  #pragma unroll
  for (int j=0;j<4;j++){
    int f = lane + j*64;
    o[f] = f2b((v[j]-m)*r*g[f] + b[f]);
  }
}

// ---------------------------------------------------------------- pooling (bf16 un -> f32)
__global__ void __launch_bounds__(256) k_pool_y(const bf16_t* __restrict__ un, float* __restrict__ pooly){
  int by = blockIdx.x;
  int d = threadIdx.x;
  size_t base = (size_t)by*NX*DIM + d;
  float s = 0.f;
  for (int x=0;x<NX;x++) s += b2f(un[base + (size_t)x*DIM]);
  pooly[(size_t)by*DIM + d] = s*(1.0f/NX);
}
__global__ void __launch_bounds__(256) k_pool_x(const bf16_t* __restrict__ un, float* __restrict__ poolx){
  int bb = blockIdx.x / NX, x = blockIdx.x % NX;
  int d = threadIdx.x;
  size_t base = ((size_t)bb*NY*NX + x)*DIM + d;
  float s = 0.f;
  for (int y=0;y<NY;y++) s += b2f(un[base + (size_t)y*NX*DIM]);
  poolx[(size_t)blockIdx.x*DIM + d] = s*(1.0f/NY);
}

// ---------------------------------------------------------------- small GEMM (all f32)
__global__ void __launch_bounds__(256) k_gemm_small(const float* __restrict__ A,
    const float* __restrict__ W, const float* __restrict__ bias,
    float* __restrict__ C, int M, int N, int K, int dogelu){
  int idx = blockIdx.x*256 + threadIdx.x;
  if (idx >= M*N) return;
  int n = idx % N, m = idx / N;
  const float* a = A + (size_t)m*K;
  float acc = 0.f;
  for (int k=0;k<K;k++) acc += a[k]*W[(size_t)k*N + n];
  if (bias) acc += bias[n];
  if (dogelu) acc = gelu_tanh(acc);
  C[idx] = acc;
}

// ---------------------------------------------------------------- RoPE split
__global__ void __launch_bounds__(256) k_rope(const float* __restrict__ qk,
    const float* __restrict__ cs, const float* __restrict__ sn,
    float* __restrict__ q, float* __restrict__ k){
  int idx = blockIdx.x*256 + threadIdx.x;
  int c = idx & 63;
  int h = (idx>>6) & 7;
  int p = (idx>>9) & 1;
  int n = (idx>>10) & 127;
  int bb = idx>>17;
  float t = qk[idx];
  float t2 = qk[(c<32) ? idx+32 : idx-32];
  if (c<32) t2 = -t2;
  float val = t*cs[n*64+c] + t2*sn[n*64+c];
  float* dst = p ? k : q;
  dst[(((size_t)bb*NH + h)*128 + n)*64 + c] = val;
}

// ---------------------------------------------------------------- attention matrix
__global__ void __launch_bounds__(128) k_attn(const float* __restrict__ q,
    const float* __restrict__ k, float* __restrict__ attn){
  int i = blockIdx.x & 127;
  int bh = blockIdx.x >> 7;
  __shared__ float qs[64];
  __shared__ float sm[128];
  int tid = threadIdx.x;
  const float* qrow = q + ((size_t)bh*128 + i)*64;
  if (tid < 64) qs[tid] = qrow[tid];
  __syncthreads();
  const float* krow = k + ((size_t)bh*128 + tid)*64;
  float dot = 0.f;
  for (int c=0;c<64;c++) dot += qs[c]*krow[c];
  dot *= (1.0f/64.0f);
  sm[tid] = dot;
  __syncthreads();
  float mx = -1e30f;
  for (int j=0;j<128;j++) mx = fmaxf(mx, sm[j]);
  __syncthreads();
  float e = expf(dot - mx);
  sm[tid] = e;
  __syncthreads();
  float s = 0.f;
  for (int j=0;j<128;j++) s += sm[j];
  attn[(size_t)blockIdx.x*128 + tid] = e/s;
}

// ---------------------------------------------------------------- fused V-projection + y-attention (scalar, unchanged)
__global__ void __launch_bounds__(256) k_phi1v(const bf16_t* __restrict__ un,
    const float* __restrict__ Wv, const float* __restrict__ attn,
    bf16_t* __restrict__ phi){
  int m  = blockIdx.x & (NX-1);
  int bh = blockIdx.x >> 7;
  int b  = bh >> 3, h = bh & 7;
  __shared__ __align__(16) bf16_t un_s[128*64];
  __shared__ __align__(16) float  wv_s[64*64];
  __shared__ __align__(16) float  v_s[128*64];
  int tid = threadIdx.x;
  int c  = tid & 63;
  int yb = tid >> 6;

  float vacc[32];
  #pragma unroll
  for (int i=0;i<32;i++) vacc[i]=0.f;

  for (int kc=0; kc<4; kc++){
    {
      const ushort* ug = (const ushort*)un;
      ushort4* dst = (ushort4*)un_s;
      #pragma unroll
      for (int j=0;j<8;j++){
        int q = tid + j*256;
        int y = q >> 4, c4 = q & 15;
        size_t ga = (((size_t)b*NY + y)*NX + m)*DIM + kc*64 + c4*4;
        dst[q] = *(const ushort4*)(ug + ga);
      }
      float4* wdst = (float4*)wv_s;
      #pragma unroll
      for (int j=0;j<4;j++){
        int q = tid + j*256;
        int k = q >> 4, c4 = q & 15;
        size_t ga = ((size_t)(kc*64 + k))*HDIM + h*64 + c4*4;
        wdst[q] = *(const float4*)(Wv + ga);
      }
    }
    __syncthreads();
    float w[64];
    #pragma unroll
    for (int k=0;k<64;k++) w[k] = wv_s[k*64 + c];
    #pragma unroll
    for (int i=0;i<32;i++){
      const ushort4* row = (const ushort4*)&un_s[(yb*32+i)*64];
      float a = vacc[i];
      #pragma unroll
      for (int j=0;j<16;j++){
        ushort4 u4 = row[j];
        a += b2f(*(const bf16_t*)&u4.x)*w[j*4+0] + b2f(*(const bf16_t*)&u4.y)*w[j*4+1]
           + b2f(*(const bf16_t*)&u4.z)*w[j*4+2] + b2f(*(const bf16_t*)&u4.w)*w[j*4+3];
      }
      vacc[i] = a;
    }
    __syncthreads();
  }
  #pragma unroll
  for (int i=0;i<32;i++) v_s[(yb*32+i)*64 + c] = vacc[i];
  __syncthreads();

  int i0 = yb*32;
  const float* arow = attn + (size_t)bh*16384 + (size_t)i0*128;
  float acc[32];
  #pragma unroll
  for (int i=0;i<32;i++) acc[i]=0.f;
  for (int j=0;j<128;j++){
    float vv = v_s[j*64 + c];
    #pragma unroll
    for (int i=0;i<32;i++) acc[i] += arow[i*128 + j]*vv;
  }
  bf16_t* pout = phi + ((size_t)bh*NY + i0)*(NX*DH_) + (size_t)m*DH_ + c;
  #pragma unroll
  for (int i=0;i<32;i++) pout[(size_t)i*(NX*DH_)] = f2b(acc[i]);
}

// ---------------------------------------------------------------- phi2 (x-attention, in place, unchanged)
__global__ void __launch_bounds__(256) k_phi2(const float* __restrict__ attn,
    bf16_t* __restrict__ phi){
  int i = blockIdx.x & (NY-1);
  int bh = blockIdx.x >> 7;
  __shared__ float ps[128*64];
  int tid = threadIdx.x;
  bf16_t* pblk = phi + ((size_t)bh*NY + i)*(NX*DH_);
  for (int t=tid; t<8192; t+=256) ps[t] = b2f(pblk[t]);
  __syncthreads();
  int c = tid & 63;
  int l0 = (tid >> 6) * 32;
  const float* arow = attn + (size_t)bh*16384 + (size_t)l0*128;
  float acc[32];
  #pragma unroll
  for (int l=0;l<32;l++) acc[l]=0.f;
  for (int mm=0; mm<128; mm++){
    float vv = ps[mm*64 + c];
    #pragma unroll
    for (int l=0;l<32;l++) acc[l] += arow[l*128 + mm]*vv;
  }
  #pragma unroll
  for (int l=0;l<32;l++) pblk[(size_t)(l0+l)*DH_ + c] = f2b(acc[l]);
}

// ---------------------------------------------------------------- GroupNorm + Wm + residual (MFMA)
// block = 64 consecutive positions (same b, same y, x = x0..x0+63), 256 thr
#define GN_STRIDE 520   // 512 + 8 pad: word-stride 260 -> bank shift 4/row
__global__ void __launch_bounds__(256) k_gn_wm(const bf16_t* __restrict__ phi,
    const short* __restrict__ WmP, const float* __restrict__ bm,
    const float* __restrict__ u, float* __restrict__ u2){
  __shared__ __align__(16) short X[64*GN_STRIDE];
  __shared__ float mean_s[512], rstd_s[512];
  int tid = threadIdx.x;
  int lane = tid & 63, w = tid >> 6;
  size_t p0 = (size_t)blockIdx.x*64;
  int b  = (int)(p0 >> 14);
  int y  = (int)((p0 >> 7) & 127);
  int x0 = (int)(p0 & 127);

  // stage phi (bf16) -> LDS
  #pragma unroll
  for (int it=0; it<32; it++){
    int q = tid + it*256;          // < 8192
    int r = q >> 7, f4 = q & 127;
    int h = f4 >> 4, c4 = f4 & 15;
    const ushort* src = (const ushort*)phi +
        ((((size_t)b*NH + h)*NY + y)*NX + (x0 + r))*DH_ + c4*4;
    *(ushort4*)&X[r*GN_STRIDE + f4*4] = *(const ushort4*)src;
  }
  __syncthreads();
  // group stats: 512 groups (row, head), 2 per thread
  #pragma unroll
  for (int gg=0; gg<2; gg++){
    int g = tid*2 + gg;
    int r = g >> 3, h = g & 7;
    const short* base = &X[r*GN_STRIDE + h*64];
    float s=0.f, ss=0.f;
    #pragma unroll
    for (int i=0;i<16;i++){
      ushort4 v4 = *(const ushort4*)&base[i*4];
      float a = s2f((short)v4.x), bq = s2f((short)v4.y), cq = s2f((short)v4.z), d = s2f((short)v4.w);
      s += a+bq+cq+d; ss += a*a+bq*bq+cq*cq+d*d;
    }
    float mm = s*(1.0f/64.0f);
    float vv = ss*(1.0f/64.0f) - mm*mm;
    mean_s[g] = mm;
    rstd_s[g] = rsqrtf(vv + 1e-6f);
  }
  __syncthreads();
  // normalize in place
  #pragma unroll
  for (int it=0; it<32; it++){
    int q = tid + it*256;
    int r = q >> 7, f4 = q & 127;
    int h = f4 >> 4;
    float mm = mean_s[r*8 + h], rs = rstd_s[r*8 + h];
    short* ptr = &X[r*GN_STRIDE + f4*4];
    ushort4 v4 = *(ushort4*)ptr;
    v4.x = (ushort)f2s((s2f((short)v4.x)-mm)*rs);
    v4.y = (ushort)f2s((s2f((short)v4.y)-mm)*rs);
    v4.z = (ushort)f2s((s2f((short)v4.z)-mm)*rs);
    v4.w = (ushort)f2s((s2f((short)v4.w)-mm)*rs);
    *(ushort4*)ptr = v4;
  }
  __syncthreads();

  // GEMM: [64 x 512] @ [512 x 256]; wave w owns cols w*64..w*64+63
  f32x4 o[4][4];
  #pragma unroll
  for (int mt=0;mt<4;mt++)
    #pragma unroll
    for (int nt=0;nt<4;nt++) o[mt][nt] = (f32x4){0.f,0.f,0.f,0.f};
  int am = lane & 15, aq = lane >> 4;
  for (int kb=0; kb<16; kb++){
    short8 a[4], bfr[4];
    #pragma unroll
    for (int mt=0;mt<4;mt++)
      a[mt] = *(const short8*)&X[(mt*16 + am)*GN_STRIDE + kb*32 + aq*8];
    #pragma unroll
    for (int nt=0;nt<4;nt++)
      bfr[nt] = *(const short8*)&WmP[(size_t)((kb*16 + (w*4+nt))*64 + lane)*8];
    #pragma unroll
    for (int mt=0;mt<4;mt++)
      #pragma unroll
      for (int nt=0;nt<4;nt++)
        o[mt][nt] = __builtin_amdgcn_mfma_f32_16x16x32_bf16(a[mt], bfr[nt], o[mt][nt], 0,0,0);
  }
  // epilogue: + bm + u
  #pragma unroll
  for (int nt=0;nt<4;nt++){
    int col = w*64 + nt*16 + am;
    float bmv = bm[col];
    #pragma unroll
    for (int mt=0;mt<4;mt++){
      #pragma unroll
      for (int reg=0;reg<4;reg++){
        size_t p = p0 + mt*16 + aq*4 + reg;
        u2[p*DIM + col] = o[mt][nt][reg] + bmv + u[p*DIM + col];
      }
    }
  }
}

// ---------------------------------------------------------------- LN2 + MLP + residual (MFMA, in-place in d_out)
// block = 64 rows; GEMM1 [64x256]@[256x1024] chunked by 256 cols, GEMM2 accumulates
#define ML_STRIDE 264   // 256 + 8 pad
__global__ void __launch_bounds__(256) k_mlp_out(float* u2,
    const float* __restrict__ g2, const float* __restrict__ b2,
    const short* __restrict__ Wf1P, const float* __restrict__ bf1,
    const short* __restrict__ Wf2P, const float* __restrict__ bf2){
  __shared__ __align__(16) short X[64*ML_STRIDE];
  __shared__ __align__(16) short H[64*ML_STRIDE];
  int tid = threadIdx.x;
  int lane = tid & 63, w = tid >> 6;
  size_t p0 = (size_t)blockIdx.x*64;

  // phase 0: LN2 -> bf16 X in LDS (wave w handles rows w*16..w*16+15)
  float4 g4 = *(const float4*)&g2[lane*4];
  float4 bq4 = *(const float4*)&b2[lane*4];
  for (int rr=0; rr<16; rr++){
    int r = w*16 + rr;
    float4 v = *(const float4*)&u2[(p0 + r)*DIM + lane*4];
    float s = v.x+v.y+v.z+v.w;
    float ss = v.x*v.x+v.y*v.y+v.z*v.z+v.w*v.w;
    #pragma unroll
    for (int off=32;off>0;off>>=1){ s += __shfl_down(s,off,64); ss += __shfl_down(ss,off,64); }
    s = __shfl(s,0,64); ss = __shfl(ss,0,64);
    float m = s*(1.0f/DIM);
    float rstd = rsqrtf(ss*(1.0f/DIM) - m*m + 1e-5f);
    ushort4 xo;
    xo.x = (ushort)f2s((v.x-m)*rstd*g4.x + bq4.x);
    xo.y = (ushort)f2s((v.y-m)*rstd*g4.y + bq4.y);
    xo.z = (ushort)f2s((v.z-m)*rstd*g4.z + bq4.z);
    xo.w = (ushort)f2s((v.w-m)*rstd*g4.w + bq4.w);
    *(ushort4*)&X[r*ML_STRIDE + lane*4] = xo;
  }
  __syncthreads();

  int am = lane & 15, aq = lane >> 4;
  f32x4 o[4][4];
  #pragma unroll
  for (int mt=0;mt<4;mt++)
    #pragma unroll
    for (int nt=0;nt<4;nt++) o[mt][nt] = (f32x4){0.f,0.f,0.f,0.f};

  for (int nc=0; nc<4; nc++){
    // GEMM1: H chunk = gelu(X @ Wf1[:, nc*256 .. +256) + bf1)
    f32x4 hacc[4][4];
    #pragma unroll
    for (int mt=0;mt<4;mt++)
      #pragma unroll
      for (int nt=0;nt<4;nt++) hacc[mt][nt] = (f32x4){0.f,0.f,0.f,0.f};
    for (int kb=0; kb<8; kb++){
      short8 a[4], bfr[4];
      #pragma unroll
      for (int mt=0;mt<4;mt++)
        a[mt] = *(const short8*)&X[(mt*16 + am)*ML_STRIDE + kb*32 + aq*8];
      #pragma unroll
      for (int nt=0;nt<4;nt++){
        int ntg = nc*16 + w*4 + nt;    // of 64 n-tiles
        bfr[nt] = *(const short8*)&Wf1P[(size_t)((kb*64 + ntg)*64 + lane)*8];
      }
      #pragma unroll
      for (int mt=0;mt<4;mt++)
        #pragma unroll
        for (int nt=0;nt<4;nt++)
          hacc[mt][nt] = __builtin_amdgcn_mfma_f32_16x16x32_bf16(a[mt], bfr[nt], hacc[mt][nt], 0,0,0);
    }
    // bias + gelu -> H (bf16)
    #pragma unroll
    for (int nt=0;nt<4;nt++){
      int col_l = w*64 + nt*16 + am;
      float bv = bf1[nc*256 + col_l];
      #pragma unroll
      for (int mt=0;mt<4;mt++){
        #pragma unroll
        for (int reg=0;reg<4;reg++){
          int row = mt*16 + aq*4 + reg;
          H[row*ML_STRIDE + col_l] = f2s(gelu_tanh(hacc[mt][nt][reg] + bv));
        }
      }
    }
    __syncthreads();
    // GEMM2 partial: O += H_chunk @ Wf2[nc*256 .. , :]
    for (int kb=0; kb<8; kb++){
      short8 a[4], bfr[4];
      #pragma unroll
      for (int mt=0;mt<4;mt++)
        a[mt] = *(const short8*)&H[(mt*16 + am)*ML_STRIDE + kb*32 + aq*8];
      int kbg = nc*8 + kb;             // of 32 k-blocks
      #pragma unroll
      for (int nt=0;nt<4;nt++)
        bfr[nt] = *(const short8*)&Wf2P[(size_t)((kbg*16 + (w*4+nt))*64 + lane)*8];
      #pragma unroll
      for (int mt=0;mt<4;mt++)
        #pragma unroll
        for (int nt=0;nt<4;nt++)
          o[mt][nt] = __builtin_amdgcn_mfma_f32_16x16x32_bf16(a[mt], bfr[nt], o[mt][nt], 0,0,0);
    }
    __syncthreads();   // before next chunk overwrites H
  }

  // epilogue: out = O + bf2 + u2 (residual), in place
  #pragma unroll
  for (int nt=0;nt<4;nt++){
    int col = w*64 + nt*16 + am;
    float bv = bf2[col];
    #pragma unroll
    for (int mt=0;mt<4;mt++){
      #pragma unroll
      for (int reg=0;reg<4;reg++){
        size_t p = p0 + mt*16 + aq*4 + reg;
        float res = u2[p*DIM + col];
        u2[p*DIM + col] = o[mt][nt][reg] + bv + res;
      }
    }
  }
}

extern "C" void kernel_launch(void* const* d_in, const int* in_sizes, int n_in,
                              void* d_out, int out_size, void* d_ws, size_t ws_size,
                              hipStream_t stream){
  const float* u    = (const float*)d_in[0];
  const float* rcy  = (const float*)d_in[1];
  const float* rsy  = (const float*)d_in[2];
  const float* rcx  = (const float*)d_in[3];
  const float* rsx  = (const float*)d_in[4];
  const float* ln1g = (const float*)d_in[6];
  const float* ln1b = (const float*)d_in[7];
  const float* ln2g = (const float*)d_in[8];
  const float* ln2b = (const float*)d_in[9];
  const float* Wv   = (const float*)d_in[10];
  const float* Wyin = (const float*)d_in[11];
  const float* Wy1  = (const float*)d_in[12];
  const float* by1  = (const float*)d_in[13];
  const float* Wy2  = (const float*)d_in[14];
  const float* by2  = (const float*)d_in[15];
  const float* Wxin = (const float*)d_in[16];
  const float* Wx1  = (const float*)d_in[17];
  const float* bx1  = (const float*)d_in[18];
  const float* Wx2  = (const float*)d_in[19];
  const float* bx2  = (const float*)d_in[20];
  const float* Wqkx = (const float*)d_in[21];
  const float* Wqky = (const float*)d_in[22];
  const float* Wm   = (const float*)d_in[23];
  const float* bm   = (const float*)d_in[24];
  const float* Wf1  = (const float*)d_in[25];
  const float* bf1  = (const float*)d_in[26];
  const float* Wf2  = (const float*)d_in[27];
  const float* bf2  = (const float*)d_in[28];

  char* w = (char*)d_ws;
  auto alloc = [&](size_t n) -> void* {
    void* p = (void*)w;
    w += (n + 255) & ~(size_t)255;
    return p;
  };
  bf16_t* UN   = (bf16_t*)alloc((size_t)NPOS*DIM*2);               // 32 MiB
  bf16_t* PHI  = (bf16_t*)alloc((size_t)NB*NH*NY*NX*DH_*2);        // 64 MiB
  float* POOLY = (float*)alloc((size_t)NB*NY*DIM*4);
  float* POOLX = (float*)alloc((size_t)NB*NX*DIM*4);
  float* TY    = (float*)alloc((size_t)512*256*4);
  float* TX    = (float*)alloc((size_t)512*256*4);
  float* HY    = (float*)alloc((size_t)512*1024*4);
  float* HX    = (float*)alloc((size_t)512*1024*4);
  float* UY    = (float*)alloc((size_t)512*256*4);
  float* UX    = (float*)alloc((size_t)512*256*4);
  float* QKY   = (float*)alloc((size_t)512*1024*4);
  float* QKX   = (float*)alloc((size_t)512*1024*4);
  float* QRY   = (float*)alloc((size_t)NB*NH*128*64*4);
  float* KRY   = (float*)alloc((size_t)NB*NH*128*64*4);
  float* QRX   = (float*)alloc((size_t)NB*NH*128*64*4);
  float* KRX   = (float*)alloc((size_t)NB*NH*128*64*4);
  float* ATTNY = (float*)alloc((size_t)NB*NH*128*128*4);
  float* ATTNX = (float*)alloc((size_t)NB*NH*128*128*4);
  short* WF1P  = (short*)alloc((size_t)256*1024*2);
  short* WF2P  = (short*)alloc((size_t)1024*256*2);
  short* WMP   = (short*)alloc((size_t)512*256*2);
  float* U2 = (float*)d_out;
  (void)in_sizes; (void)n_in; (void)out_size; (void)ws_size;

  // one-time weight packs (cheap; run every call for graph-capture safety)
  k_pack<<<(256*1024/8)/256, 256, 0, stream>>>(Wf1, WF1P, 256, 1024);
  k_pack<<<(1024*256/8)/256, 256, 0, stream>>>(Wf2, WF2P, 1024, 256);
  k_pack<<<(512*256/8)/256, 256, 0, stream>>>(Wm, WMP, 512, 256);

  k_ln1<<<NPOS/4, 256, 0, stream>>>(u, ln1g, ln1b, UN);
  k_pool_y<<<NB*NY, 256, 0, stream>>>(UN, POOLY);
  k_pool_x<<<NB*NX, 256, 0, stream>>>(UN, POOLX);
  k_gemm_small<<<(512*256)/256, 256, 0, stream>>>(POOLY, Wyin, (const float*)nullptr, TY, 512, 256, 256, 0);
  k_gemm_small<<<(512*1024)/256, 256, 0, stream>>>(TY, Wy1, by1, HY, 512, 1024, 256, 1);
  k_gemm_small<<<(512*256)/256, 256, 0, stream>>>(HY, Wy2, by2, UY, 512, 256, 1024, 0);
  k_gemm_small<<<(512*1024)/256, 256, 0, stream>>>(UY, Wqky, (const float*)nullptr, QKY, 512, 1024, 256, 0);
  k_gemm_small<<<(512*256)/256, 256, 0, stream>>>(POOLX, Wxin, (const float*)nullptr, TX, 512, 256, 256, 0);
  k_gemm_small<<<(512*1024)/256, 256, 0, stream>>>(TX, Wx1, bx1, HX, 512, 1024, 256, 1);
  k_gemm_small<<<(512*256)/256, 256, 0, stream>>>(HX, Wx2, bx2, UX, 512, 256, 1024, 0);
  k_gemm_small<<<(512*1024)/256, 256, 0, stream>>>(UX, Wqkx, (const float*)nullptr, QKX, 512, 1024, 256, 0);
  k_rope<<<(NB*128*1024)/256, 256, 0, stream>>>(QKY, rcy, rsy, QRY, KRY);
  k_rope<<<(NB*128*1024)/256, 256, 0, stream>>>(QKX, rcx, rsx, QRX, KRX);
  k_attn<<<NB*NH*128, 128, 0, stream>>>(QRY, KRY, ATTNY);
  k_attn<<<NB*NH*128, 128, 0, stream>>>(QRX, KRX, ATTNX);
  k_phi1v<<<NB*NH*NX, 256, 0, stream>>>(UN, Wv, ATTNY, PHI);
  k_phi2<<<NB*NH*NY, 256, 0, stream>>>(ATTNX, PHI);
  k_gn_wm<<<NPOS/64, 256, 0, stream>>>(PHI, WMP, bm, u, U2);
  k_mlp_out<<<NPOS/64, 256, 0, stream>>>(U2, ln2g, ln2b, WF1P, bf1, WF2P, bf2);
}

// Round 6
// 2015.981 us; speedup vs baseline: 2.2914x; 1.6003x over previous
//
#include <hip/hip_runtime.h>
#include <hip/hip_bf16.h>
#include <math.h>

// Problem constants (B=4, 128x128 grid, DIM=256, 8 heads x 64)
#define NB 4
#define NY 128
#define NX 128
#define DIM 256
#define NH 8
#define DH_ 64
#define HDIM 512   // NH*DH
#define HID 1024
#define NPOS (NB*NY*NX)   // 65536

typedef __hip_bfloat16 bf16_t;
typedef __attribute__((ext_vector_type(8))) short short8;   // 8 bf16 = 1 MFMA A/B frag
typedef __attribute__((ext_vector_type(4))) float f32x4;    // MFMA C/D frag

__device__ __forceinline__ float b2f(bf16_t x){ return __bfloat162float(x); }
__device__ __forceinline__ bf16_t f2b(float x){ return __float2bfloat16(x); }
__device__ __forceinline__ short f2s(float x){ bf16_t h = __float2bfloat16(x); return *reinterpret_cast<short*>(&h); }
__device__ __forceinline__ float s2f(short x){ bf16_t h = *reinterpret_cast<bf16_t*>(&x); return __bfloat162float(h); }

// MFMA fragment layout (gfx950, verified in-round 3->4):
//  A[m][k]: m = lane&15, k = (lane>>4)*8 + j
//  B[k][n]: n = lane&15, k = (lane>>4)*8 + j
//  D[row][col]: col = lane&15, row = (lane>>4)*4 + reg

__device__ __forceinline__ float gelu_tanh(float x){
  float x3 = x*x*x;
  return 0.5f*x*(1.0f + tanhf(0.7978845608028654f*(x + 0.044715f*x3)));
}

// ---------------------------------------------------------------- weight pack
// W[K x N] f32 row-major -> bf16 B-fragment order
__global__ void __launch_bounds__(256) k_pack(const float* __restrict__ W,
    short* __restrict__ out, int K, int N){
  int tid = blockIdx.x*256 + threadIdx.x;      // < K*N/8
  int lane = tid & 63;
  int rem = tid >> 6;
  int ntiles = N >> 4;
  int nt = rem % ntiles, kb = rem / ntiles;
  int n = nt*16 + (lane & 15);
  int k0 = kb*32 + (lane>>4)*8;
  short8 v;
  #pragma unroll
  for (int j=0;j<8;j++) v[j] = f2s(W[(size_t)(k0+j)*N + n]);
  *(short8*)&out[(size_t)tid*8] = v;
}

// ---------------------------------------------------------------- LN1 (f32 in -> bf16 un)
__global__ void __launch_bounds__(256) k_ln1(const float* __restrict__ u,
    const float* __restrict__ g, const float* __restrict__ b,
    bf16_t* __restrict__ un){
  int wave = threadIdx.x >> 6, lane = threadIdx.x & 63;
  size_t row = (size_t)blockIdx.x*4 + wave;
  const float* x = u + row*DIM;
  float v[4]; float s=0.f, ss=0.f;
  #pragma unroll
  for (int j=0;j<4;j++){ float t = x[lane + j*64]; v[j]=t; s+=t; ss+=t*t; }
  #pragma unroll
  for (int off=32;off>0;off>>=1){ s += __shfl_down(s,off,64); ss += __shfl_down(ss,off,64); }
  s = __shfl(s,0,64); ss = __shfl(ss,0,64);
  float m = s*(1.0f/DIM);
  float var = ss*(1.0f/DIM) - m*m;
  float r = rsqrtf(var + 1e-5f);
  bf16_t* o = un + row*DIM;
  #pragma unroll
  for (int j=0;j<4;j++){
    int f = lane + j*64;
    o[f] = f2b((v[j]-m)*r*g[f] + b[f]);
  }
}

// ---------------------------------------------------------------- pooling (bf16 un -> f32)
__global__ void __launch_bounds__(256) k_pool_y(const bf16_t* __restrict__ un, float* __restrict__ pooly){
  int by = blockIdx.x;
  int d = threadIdx.x;
  size_t base = (size_t)by*NX*DIM + d;
  float s = 0.f;
  for (int x=0;x<NX;x++) s += b2f(un[base + (size_t)x*DIM]);
  pooly[(size_t)by*DIM + d] = s*(1.0f/NX);
}
__global__ void __launch_bounds__(256) k_pool_x(const bf16_t* __restrict__ un, float* __restrict__ poolx){
  int bb = blockIdx.x / NX, x = blockIdx.x % NX;
  int d = threadIdx.x;
  size_t base = ((size_t)bb*NY*NX + x)*DIM + d;
  float s = 0.f;
  for (int y=0;y<NY;y++) s += b2f(un[base + (size_t)y*NX*DIM]);
  poolx[(size_t)blockIdx.x*DIM + d] = s*(1.0f/NY);
}

// ---------------------------------------------------------------- small GEMM (all f32)
__global__ void __launch_bounds__(256) k_gemm_small(const float* __restrict__ A,
    const float* __restrict__ W, const float* __restrict__ bias,
    float* __restrict__ C, int M, int N, int K, int dogelu){
  int idx = blockIdx.x*256 + threadIdx.x;
  if (idx >= M*N) return;
  int n = idx % N, m = idx / N;
  const float* a = A + (size_t)m*K;
  float acc = 0.f;
  for (int k=0;k<K;k++) acc += a[k]*W[(size_t)k*N + n];
  if (bias) acc += bias[n];
  if (dogelu) acc = gelu_tanh(acc);
  C[idx] = acc;
}

// ---------------------------------------------------------------- RoPE split
__global__ void __launch_bounds__(256) k_rope(const float* __restrict__ qk,
    const float* __restrict__ cs, const float* __restrict__ sn,
    float* __restrict__ q, float* __restrict__ k){
  int idx = blockIdx.x*256 + threadIdx.x;
  int c = idx & 63;
  int h = (idx>>6) & 7;
  int p = (idx>>9) & 1;
  int n = (idx>>10) & 127;
  int bb = idx>>17;
  float t = qk[idx];
  float t2 = qk[(c<32) ? idx+32 : idx-32];
  if (c<32) t2 = -t2;
  float val = t*cs[n*64+c] + t2*sn[n*64+c];
  float* dst = p ? k : q;
  dst[(((size_t)bb*NH + h)*128 + n)*64 + c] = val;
}

// ---------------------------------------------------------------- attention matrix (bf16 out)
__global__ void __launch_bounds__(128) k_attn(const float* __restrict__ q,
    const float* __restrict__ k, bf16_t* __restrict__ attn){
  int i = blockIdx.x & 127;
  int bh = blockIdx.x >> 7;
  __shared__ float qs[64];
  __shared__ float sm[128];
  int tid = threadIdx.x;
  const float* qrow = q + ((size_t)bh*128 + i)*64;
  if (tid < 64) qs[tid] = qrow[tid];
  __syncthreads();
  const float* krow = k + ((size_t)bh*128 + tid)*64;
  float dot = 0.f;
  for (int c=0;c<64;c++) dot += qs[c]*krow[c];
  dot *= (1.0f/64.0f);
  sm[tid] = dot;
  __syncthreads();
  float mx = -1e30f;
  for (int j=0;j<128;j++) mx = fmaxf(mx, sm[j]);
  __syncthreads();
  float e = expf(dot - mx);
  sm[tid] = e;
  __syncthreads();
  float s = 0.f;
  for (int j=0;j<128;j++) s += sm[j];
  attn[(size_t)blockIdx.x*128 + tid] = f2b(e/s);
}

// ---------------------------------------------------------------- MFMA phi1: V-proj + y-attention
// block (bh, m=x): V[y][c] = un[b,y,m,:] @ Wv[:, h*64+c]  (K=256, MFMA)
//                  P1[i][c] = attnY[bh,i,:] @ V[:,c]      (K=128, MFMA)
// phi layout out: [bh][i][m][c]
#define AST 136   // 128 + 8 shorts
#define UST 72    // 64 + 8 shorts
#define VST 136
__global__ void __launch_bounds__(256) k_phi1m(const bf16_t* __restrict__ un,
    const short* __restrict__ WvP, const bf16_t* __restrict__ attn,
    bf16_t* __restrict__ phi){
  int m  = blockIdx.x & (NX-1);
  int bh = blockIdx.x >> 7;
  int b  = bh >> 3, h = bh & 7;
  __shared__ __align__(16) short At[128*AST];   // 34.8 KB
  __shared__ __align__(16) short unc[128*UST];  // 18.4 KB
  __shared__ __align__(16) short Vt[64*VST];    // 17.4 KB  [c][y]
  int tid = threadIdx.x;
  int lane = tid & 63, w = tid >> 6;
  int am = lane & 15, aq = lane >> 4;

  // stage attn slice (bh): 128x128 bf16 -> At (read only in phase 2)
  {
    const ushort* ag = (const ushort*)attn + (size_t)bh*16384;
    #pragma unroll
    for (int it=0; it<16; it++){
      int q = tid + it*256;          // < 4096 ushort4
      int i = q >> 5, j4 = q & 31;
      *(ushort4*)&At[i*AST + j4*4] = *(const ushort4*)(ag + i*128 + j4*4);
    }
  }

  // ---- phase 1: V-projection (wave w owns y rows w*32..+31, all 64 c)
  f32x4 v[2][4];
  #pragma unroll
  for (int mt=0;mt<2;mt++)
    #pragma unroll
    for (int nt=0;nt<4;nt++) v[mt][nt] = (f32x4){0.f,0.f,0.f,0.f};
  const ushort* ug = (const ushort*)un;
  for (int kc=0; kc<4; kc++){
    #pragma unroll
    for (int it=0; it<8; it++){
      int q = tid + it*256;          // < 2048 ushort4
      int y = q >> 4, c4 = q & 15;
      *(ushort4*)&unc[y*UST + c4*4] =
          *(const ushort4*)(ug + (((size_t)b*NY + y)*NX + m)*DIM + kc*64 + c4*4);
    }
    __syncthreads();
    #pragma unroll
    for (int kb=0; kb<2; kb++){
      short8 a2[2], bb[4];
      #pragma unroll
      for (int mt=0;mt<2;mt++)
        a2[mt] = *(const short8*)&unc[(w*32 + mt*16 + am)*UST + kb*32 + aq*8];
      int kbg = kc*2 + kb;           // of 8
      #pragma unroll
      for (int nt=0;nt<4;nt++)
        bb[nt] = *(const short8*)&WvP[(size_t)((kbg*32 + (h*4+nt))*64 + lane)*8];
      #pragma unroll
      for (int mt=0;mt<2;mt++)
        #pragma unroll
        for (int nt=0;nt<4;nt++)
          v[mt][nt] = __builtin_amdgcn_mfma_f32_16x16x32_bf16(a2[mt], bb[nt], v[mt][nt], 0,0,0);
    }
    __syncthreads();
  }
  // V frags -> Vt transposed [c][y] (4 consecutive y per frag -> ushort4)
  #pragma unroll
  for (int mt=0;mt<2;mt++)
    #pragma unroll
    for (int nt=0;nt<4;nt++){
      int c = nt*16 + am;
      int y0 = w*32 + mt*16 + aq*4;
      ushort4 pk;
      pk.x = (ushort)f2s(v[mt][nt][0]);
      pk.y = (ushort)f2s(v[mt][nt][1]);
      pk.z = (ushort)f2s(v[mt][nt][2]);
      pk.w = (ushort)f2s(v[mt][nt][3]);
      *(ushort4*)&Vt[c*VST + y0] = pk;
    }
  __syncthreads();

  // ---- phase 2: P1 = attnY @ V (rows i = w*32..+31, cols 64 c, K=128)
  f32x4 o[2][4];
  #pragma unroll
  for (int mt=0;mt<2;mt++)
    #pragma unroll
    for (int nt=0;nt<4;nt++) o[mt][nt] = (f32x4){0.f,0.f,0.f,0.f};
  #pragma unroll
  for (int kb=0; kb<4; kb++){
    short8 a2[2], bb[4];
    #pragma unroll
    for (int mt=0;mt<2;mt++)
      a2[mt] = *(const short8*)&At[(w*32 + mt*16 + am)*AST + kb*32 + aq*8];
    #pragma unroll
    for (int nt=0;nt<4;nt++)
      bb[nt] = *(const short8*)&Vt[(nt*16 + am)*VST + kb*32 + aq*8];
    #pragma unroll
    for (int mt=0;mt<2;mt++)
      #pragma unroll
      for (int nt=0;nt<4;nt++)
        o[mt][nt] = __builtin_amdgcn_mfma_f32_16x16x32_bf16(a2[mt], bb[nt], o[mt][nt], 0,0,0);
  }
  // write P1 -> phi[bh][i][m][c]
  ushort* pg = (ushort*)phi + (size_t)bh*NY*NX*DH_ + (size_t)m*DH_;
  #pragma unroll
  for (int mt=0;mt<2;mt++)
    #pragma unroll
    for (int nt=0;nt<4;nt++)
      #pragma unroll
      for (int reg=0;reg<4;reg++){
        int i = w*32 + mt*16 + aq*4 + reg;
        int c = nt*16 + am;
        pg[(size_t)i*(NX*DH_) + c] = (ushort)f2s(o[mt][nt][reg]);
      }
}

// ---------------------------------------------------------------- MFMA phi2: x-attention, in place
// block (bh, i): P2[l][c] = attnX[bh,l,:] @ P1[i,:,c]; slice [m][c] -> Pt[c][m]
__global__ void __launch_bounds__(256) k_phi2m(const bf16_t* __restrict__ attn,
    bf16_t* __restrict__ phi){
  int i  = blockIdx.x & (NY-1);
  int bh = blockIdx.x >> 7;
  __shared__ __align__(16) short Ax[128*AST];   // 34.8 KB
  __shared__ __align__(16) short Pt[64*VST];    // 17.4 KB  [c][m]
  int tid = threadIdx.x;
  int lane = tid & 63, w = tid >> 6;
  int am = lane & 15, aq = lane >> 4;

  {
    const ushort* ag = (const ushort*)attn + (size_t)bh*16384;
    #pragma unroll
    for (int it=0; it<16; it++){
      int q = tid + it*256;
      int r = q >> 5, j4 = q & 31;
      *(ushort4*)&Ax[r*AST + j4*4] = *(const ushort4*)(ag + r*128 + j4*4);
    }
  }
  ushort* pg = (ushort*)phi + (size_t)(bh*NY + i)*(NX*DH_);
  // FIX (round-5 NaN): slice is 128x64 shorts = 2048 ushort4 -> 8 iterations,
  // NOT 16. The old bound read past the slice (and past PHI for the last
  // block, pulling f32 halves that decode to bf16 NaN) and overflowed Pt.
  #pragma unroll
  for (int it=0; it<8; it++){
    int q = tid + it*256;            // < 2048 ushort4
    int mm = q >> 4, c4 = q & 15;    // mm in [0,128), c4 in [0,16)
    ushort4 v4 = *(const ushort4*)(pg + mm*DH_ + c4*4);
    Pt[(c4*4+0)*VST + mm] = v4.x;
    Pt[(c4*4+1)*VST + mm] = v4.y;
    Pt[(c4*4+2)*VST + mm] = v4.z;
    Pt[(c4*4+3)*VST + mm] = v4.w;
  }
  __syncthreads();

  f32x4 o[2][4];
  #pragma unroll
  for (int mt=0;mt<2;mt++)
    #pragma unroll
    for (int nt=0;nt<4;nt++) o[mt][nt] = (f32x4){0.f,0.f,0.f,0.f};
  #pragma unroll
  for (int kb=0; kb<4; kb++){
    short8 a2[2], bb[4];
    #pragma unroll
    for (int mt=0;mt<2;mt++)
      a2[mt] = *(const short8*)&Ax[(w*32 + mt*16 + am)*AST + kb*32 + aq*8];
    #pragma unroll
    for (int nt=0;nt<4;nt++)
      bb[nt] = *(const short8*)&Pt[(nt*16 + am)*VST + kb*32 + aq*8];
    #pragma unroll
    for (int mt=0;mt<2;mt++)
      #pragma unroll
      for (int nt=0;nt<4;nt++)
        o[mt][nt] = __builtin_amdgcn_mfma_f32_16x16x32_bf16(a2[mt], bb[nt], o[mt][nt], 0,0,0);
  }
  // write P2 in place: phi[bh][i][l][c]
  #pragma unroll
  for (int mt=0;mt<2;mt++)
    #pragma unroll
    for (int nt=0;nt<4;nt++)
      #pragma unroll
      for (int reg=0;reg<4;reg++){
        int l = w*32 + mt*16 + aq*4 + reg;
        int c = nt*16 + am;
        pg[(size_t)l*DH_ + c] = (ushort)f2s(o[mt][nt][reg]);
      }
}

// ---------------------------------------------------------------- GroupNorm + Wm + residual (MFMA)
#define GN_STRIDE 520
__global__ void __launch_bounds__(256) k_gn_wm(const bf16_t* __restrict__ phi,
    const short* __restrict__ WmP, const float* __restrict__ bm,
    const float* __restrict__ u, float* __restrict__ u2){
  __shared__ __align__(16) short X[64*GN_STRIDE];
  __shared__ float mean_s[512], rstd_s[512];
  int tid = threadIdx.x;
  int lane = tid & 63, w = tid >> 6;
  size_t p0 = (size_t)blockIdx.x*64;
  int b  = (int)(p0 >> 14);
  int y  = (int)((p0 >> 7) & 127);
  int x0 = (int)(p0 & 127);

  #pragma unroll
  for (int it=0; it<32; it++){
    int q = tid + it*256;
    int r = q >> 7, f4 = q & 127;
    int h = f4 >> 4, c4 = f4 & 15;
    const ushort* src = (const ushort*)phi +
        ((((size_t)b*NH + h)*NY + y)*NX + (x0 + r))*DH_ + c4*4;
    *(ushort4*)&X[r*GN_STRIDE + f4*4] = *(const ushort4*)src;
  }
  __syncthreads();
  #pragma unroll
  for (int gg=0; gg<2; gg++){
    int g = tid*2 + gg;
    int r = g >> 3, h = g & 7;
    const short* base = &X[r*GN_STRIDE + h*64];
    float s=0.f, ss=0.f;
    #pragma unroll
    for (int i=0;i<16;i++){
      ushort4 v4 = *(const ushort4*)&base[i*4];
      float a = s2f((short)v4.x), bq = s2f((short)v4.y), cq = s2f((short)v4.z), d = s2f((short)v4.w);
      s += a+bq+cq+d; ss += a*a+bq*bq+cq*cq+d*d;
    }
    float mm = s*(1.0f/64.0f);
    float vv = ss*(1.0f/64.0f) - mm*mm;
    mean_s[g] = mm;
    rstd_s[g] = rsqrtf(vv + 1e-6f);
  }
  __syncthreads();
  #pragma unroll
  for (int it=0; it<32; it++){
    int q = tid + it*256;
    int r = q >> 7, f4 = q & 127;
    int h = f4 >> 4;
    float mm = mean_s[r*8 + h], rs = rstd_s[r*8 + h];
    short* ptr = &X[r*GN_STRIDE + f4*4];
    ushort4 v4 = *(ushort4*)ptr;
    v4.x = (ushort)f2s((s2f((short)v4.x)-mm)*rs);
    v4.y = (ushort)f2s((s2f((short)v4.y)-mm)*rs);
    v4.z = (ushort)f2s((s2f((short)v4.z)-mm)*rs);
    v4.w = (ushort)f2s((s2f((short)v4.w)-mm)*rs);
    *(ushort4*)ptr = v4;
  }
  __syncthreads();

  f32x4 o[4][4];
  #pragma unroll
  for (int mt=0;mt<4;mt++)
    #pragma unroll
    for (int nt=0;nt<4;nt++) o[mt][nt] = (f32x4){0.f,0.f,0.f,0.f};
  int am = lane & 15, aq = lane >> 4;
  for (int kb=0; kb<16; kb++){
    short8 a[4], bfr[4];
    #pragma unroll
    for (int mt=0;mt<4;mt++)
      a[mt] = *(const short8*)&X[(mt*16 + am)*GN_STRIDE + kb*32 + aq*8];
    #pragma unroll
    for (int nt=0;nt<4;nt++)
      bfr[nt] = *(const short8*)&WmP[(size_t)((kb*16 + (w*4+nt))*64 + lane)*8];
    #pragma unroll
    for (int mt=0;mt<4;mt++)
      #pragma unroll
      for (int nt=0;nt<4;nt++)
        o[mt][nt] = __builtin_amdgcn_mfma_f32_16x16x32_bf16(a[mt], bfr[nt], o[mt][nt], 0,0,0);
  }
  #pragma unroll
  for (int nt=0;nt<4;nt++){
    int col = w*64 + nt*16 + am;
    float bmv = bm[col];
    #pragma unroll
    for (int mt=0;mt<4;mt++){
      #pragma unroll
      for (int reg=0;reg<4;reg++){
        size_t p = p0 + mt*16 + aq*4 + reg;
        u2[p*DIM + col] = o[mt][nt][reg] + bmv + u[p*DIM + col];
      }
    }
  }
}

// ---------------------------------------------------------------- LN2 + MLP + residual (MFMA, in-place in d_out)
#define ML_STRIDE 264
__global__ void __launch_bounds__(256) k_mlp_out(float* u2,
    const float* __restrict__ g2, const float* __restrict__ b2,
    const short* __restrict__ Wf1P, const float* __restrict__ bf1,
    const short* __restrict__ Wf2P, const float* __restrict__ bf2){
  __shared__ __align__(16) short X[64*ML_STRIDE];
  __shared__ __align__(16) short H[64*ML_STRIDE];
  int tid = threadIdx.x;
  int lane = tid & 63, w = tid >> 6;
  size_t p0 = (size_t)blockIdx.x*64;

  float4 g4 = *(const float4*)&g2[lane*4];
  float4 bq4 = *(const float4*)&b2[lane*4];
  for (int rr=0; rr<16; rr++){
    int r = w*16 + rr;
    float4 v = *(const float4*)&u2[(p0 + r)*DIM + lane*4];
    float s = v.x+v.y+v.z+v.w;
    float ss = v.x*v.x+v.y*v.y+v.z*v.z+v.w*v.w;
    #pragma unroll
    for (int off=32;off>0;off>>=1){ s += __shfl_down(s,off,64); ss += __shfl_down(ss,off,64); }
    s = __shfl(s,0,64); ss = __shfl(ss,0,64);
    float m = s*(1.0f/DIM);
    float rstd = rsqrtf(ss*(1.0f/DIM) - m*m + 1e-5f);
    ushort4 xo;
    xo.x = (ushort)f2s((v.x-m)*rstd*g4.x + bq4.x);
    xo.y = (ushort)f2s((v.y-m)*rstd*g4.y + bq4.y);
    xo.z = (ushort)f2s((v.z-m)*rstd*g4.z + bq4.z);
    xo.w = (ushort)f2s((v.w-m)*rstd*g4.w + bq4.w);
    *(ushort4*)&X[r*ML_STRIDE + lane*4] = xo;
  }
  __syncthreads();

  int am = lane & 15, aq = lane >> 4;
  f32x4 o[4][4];
  #pragma unroll
  for (int mt=0;mt<4;mt++)
    #pragma unroll
    for (int nt=0;nt<4;nt++) o[mt][nt] = (f32x4){0.f,0.f,0.f,0.f};

  for (int nc=0; nc<4; nc++){
    f32x4 hacc[4][4];
    #pragma unroll
    for (int mt=0;mt<4;mt++)
      #pragma unroll
      for (int nt=0;nt<4;nt++) hacc[mt][nt] = (f32x4){0.f,0.f,0.f,0.f};
    for (int kb=0; kb<8; kb++){
      short8 a[4], bfr[4];
      #pragma unroll
      for (int mt=0;mt<4;mt++)
        a[mt] = *(const short8*)&X[(mt*16 + am)*ML_STRIDE + kb*32 + aq*8];
      #pragma unroll
      for (int nt=0;nt<4;nt++){
        int ntg = nc*16 + w*4 + nt;
        bfr[nt] = *(const short8*)&Wf1P[(size_t)((kb*64 + ntg)*64 + lane)*8];
      }
      #pragma unroll
      for (int mt=0;mt<4;mt++)
        #pragma unroll
        for (int nt=0;nt<4;nt++)
          hacc[mt][nt] = __builtin_amdgcn_mfma_f32_16x16x32_bf16(a[mt], bfr[nt], hacc[mt][nt], 0,0,0);
    }
    #pragma unroll
    for (int nt=0;nt<4;nt++){
      int col_l = w*64 + nt*16 + am;
      float bv = bf1[nc*256 + col_l];
      #pragma unroll
      for (int mt=0;mt<4;mt++){
        #pragma unroll
        for (int reg=0;reg<4;reg++){
          int row = mt*16 + aq*4 + reg;
          H[row*ML_STRIDE + col_l] = f2s(gelu_tanh(hacc[mt][nt][reg] + bv));
        }
      }
    }
    __syncthreads();
    for (int kb=0; kb<8; kb++){
      short8 a[4], bfr[4];
      #pragma unroll
      for (int mt=0;mt<4;mt++)
        a[mt] = *(const short8*)&H[(mt*16 + am)*ML_STRIDE + kb*32 + aq*8];
      int kbg = nc*8 + kb;
      #pragma unroll
      for (int nt=0;nt<4;nt++)
        bfr[nt] = *(const short8*)&Wf2P[(size_t)((kbg*16 + (w*4+nt))*64 + lane)*8];
      #pragma unroll
      for (int mt=0;mt<4;mt++)
        #pragma unroll
        for (int nt=0;nt<4;nt++)
          o[mt][nt] = __builtin_amdgcn_mfma_f32_16x16x32_bf16(a[mt], bfr[nt], o[mt][nt], 0,0,0);
    }
    __syncthreads();
  }

  #pragma unroll
  for (int nt=0;nt<4;nt++){
    int col = w*64 + nt*16 + am;
    float bv = bf2[col];
    #pragma unroll
    for (int mt=0;mt<4;mt++){
      #pragma unroll
      for (int reg=0;reg<4;reg++){
        size_t p = p0 + mt*16 + aq*4 + reg;
        float res = u2[p*DIM + col];
        u2[p*DIM + col] = o[mt][nt][reg] + bv + res;
      }
    }
  }
}

extern "C" void kernel_launch(void* const* d_in, const int* in_sizes, int n_in,
                              void* d_out, int out_size, void* d_ws, size_t ws_size,
                              hipStream_t stream){
  const float* u    = (const float*)d_in[0];
  const float* rcy  = (const float*)d_in[1];
  const float* rsy  = (const float*)d_in[2];
  const float* rcx  = (const float*)d_in[3];
  const float* rsx  = (const float*)d_in[4];
  const float* ln1g = (const float*)d_in[6];
  const float* ln1b = (const float*)d_in[7];
  const float* ln2g = (const float*)d_in[8];
  const float* ln2b = (const float*)d_in[9];
  const float* Wv   = (const float*)d_in[10];
  const float* Wyin = (const float*)d_in[11];
  const float* Wy1  = (const float*)d_in[12];
  const float* by1  = (const float*)d_in[13];
  const float* Wy2  = (const float*)d_in[14];
  const float* by2  = (const float*)d_in[15];
  const float* Wxin = (const float*)d_in[16];
  const float* Wx1  = (const float*)d_in[17];
  const float* bx1  = (const float*)d_in[18];
  const float* Wx2  = (const float*)d_in[19];
  const float* bx2  = (const float*)d_in[20];
  const float* Wqkx = (const float*)d_in[21];
  const float* Wqky = (const float*)d_in[22];
  const float* Wm   = (const float*)d_in[23];
  const float* bm   = (const float*)d_in[24];
  const float* Wf1  = (const float*)d_in[25];
  const float* bf1  = (const float*)d_in[26];
  const float* Wf2  = (const float*)d_in[27];
  const float* bf2  = (const float*)d_in[28];

  char* w = (char*)d_ws;
  auto alloc = [&](size_t n) -> void* {
    void* p = (void*)w;
    w += (n + 255) & ~(size_t)255;
    return p;
  };
  bf16_t* UN   = (bf16_t*)alloc((size_t)NPOS*DIM*2);               // 32 MiB
  bf16_t* PHI  = (bf16_t*)alloc((size_t)NB*NH*NY*NX*DH_*2);        // 64 MiB
  float* POOLY = (float*)alloc((size_t)NB*NY*DIM*4);
  float* POOLX = (float*)alloc((size_t)NB*NX*DIM*4);
  float* TY    = (float*)alloc((size_t)512*256*4);
  float* TX    = (float*)alloc((size_t)512*256*4);
  float* HY    = (float*)alloc((size_t)512*1024*4);
  float* HX    = (float*)alloc((size_t)512*1024*4);
  float* UY    = (float*)alloc((size_t)512*256*4);
  float* UX    = (float*)alloc((size_t)512*256*4);
  float* QKY   = (float*)alloc((size_t)512*1024*4);
  float* QKX   = (float*)alloc((size_t)512*1024*4);
  float* QRY   = (float*)alloc((size_t)NB*NH*128*64*4);
  float* KRY   = (float*)alloc((size_t)NB*NH*128*64*4);
  float* QRX   = (float*)alloc((size_t)NB*NH*128*64*4);
  float* KRX   = (float*)alloc((size_t)NB*NH*128*64*4);
  bf16_t* ATTNY = (bf16_t*)alloc((size_t)NB*NH*128*128*2);
  bf16_t* ATTNX = (bf16_t*)alloc((size_t)NB*NH*128*128*2);
  short* WF1P  = (short*)alloc((size_t)256*1024*2);
  short* WF2P  = (short*)alloc((size_t)1024*256*2);
  short* WMP   = (short*)alloc((size_t)512*256*2);
  short* WVP   = (short*)alloc((size_t)256*512*2);
  float* U2 = (float*)d_out;
  (void)in_sizes; (void)n_in; (void)out_size; (void)ws_size;

  k_pack<<<(256*1024/8)/256, 256, 0, stream>>>(Wf1, WF1P, 256, 1024);
  k_pack<<<(1024*256/8)/256, 256, 0, stream>>>(Wf2, WF2P, 1024, 256);
  k_pack<<<(512*256/8)/256, 256, 0, stream>>>(Wm, WMP, 512, 256);
  k_pack<<<(256*512/8)/256, 256, 0, stream>>>(Wv, WVP, 256, 512);

  k_ln1<<<NPOS/4, 256, 0, stream>>>(u, ln1g, ln1b, UN);
  k_pool_y<<<NB*NY, 256, 0, stream>>>(UN, POOLY);
  k_pool_x<<<NB*NX, 256, 0, stream>>>(UN, POOLX);
  k_gemm_small<<<(512*256)/256, 256, 0, stream>>>(POOLY, Wyin, (const float*)nullptr, TY, 512, 256, 256, 0);
  k_gemm_small<<<(512*1024)/256, 256, 0, stream>>>(TY, Wy1, by1, HY, 512, 1024, 256, 1);
  k_gemm_small<<<(512*256)/256, 256, 0, stream>>>(HY, Wy2, by2, UY, 512, 256, 1024, 0);
  k_gemm_small<<<(512*1024)/256, 256, 0, stream>>>(UY, Wqky, (const float*)nullptr, QKY, 512, 1024, 256, 0);
  k_gemm_small<<<(512*256)/256, 256, 0, stream>>>(POOLX, Wxin, (const float*)nullptr, TX, 512, 256, 256, 0);
  k_gemm_small<<<(512*1024)/256, 256, 0, stream>>>(TX, Wx1, bx1, HX, 512, 1024, 256, 1);
  k_gemm_small<<<(512*256)/256, 256, 0, stream>>>(HX, Wx2, bx2, UX, 512, 256, 1024, 0);
  k_gemm_small<<<(512*1024)/256, 256, 0, stream>>>(UX, Wqkx, (const float*)nullptr, QKX, 512, 1024, 256, 0);
  k_rope<<<(NB*128*1024)/256, 256, 0, stream>>>(QKY, rcy, rsy, QRY, KRY);
  k_rope<<<(NB*128*1024)/256, 256, 0, stream>>>(QKX, rcx, rsx, QRX, KRX);
  k_attn<<<NB*NH*128, 128, 0, stream>>>(QRY, KRY, ATTNY);
  k_attn<<<NB*NH*128, 128, 0, stream>>>(QRX, KRX, ATTNX);
  k_phi1m<<<NB*NH*NX, 256, 0, stream>>>(UN, WVP, ATTNY, PHI);
  k_phi2m<<<NB*NH*NY, 256, 0, stream>>>(ATTNX, PHI);
  k_gn_wm<<<NPOS/64, 256, 0, stream>>>(PHI, WMP, bm, u, U2);
  k_mlp_out<<<NPOS/64, 256, 0, stream>>>(U2, ln2g, ln2b, WF1P, bf1, WF2P, bf2);
}